// Round 10
// baseline (115.923 us; speedup 1.0000x reference)
//
#include <hip/hip_runtime.h>

#define HH 128
#define WW 128
#define CC 64
#define KD 16
#define HW (HH * WW)
#define HWB (HW * 4)
#define TOTBYTES (4u * CC * HW * 4u)   // B=4 * C=64 * H*W * 4B = 16.78 MB
#define OOB_SENT 0x40000000            // always-OOB voffset -> HW returns 0

typedef __attribute__((ext_vector_type(4))) int   int32x4_t;
typedef __attribute__((ext_vector_type(4))) float floatx4;
typedef __attribute__((ext_vector_type(2))) float floatx2;
typedef _Float16 f16x8 __attribute__((ext_vector_type(8)));

__device__ floatx4 llvm_amdgcn_raw_buffer_load_v4f32(int32x4_t srsrc, int voffset,
                                                     int soffset, int aux)
    __asm("llvm.amdgcn.raw.buffer.load.v4f32");
__device__ floatx2 llvm_amdgcn_raw_buffer_load_v2f32(int32x4_t srsrc, int voffset,
                                                     int soffset, int aux)
    __asm("llvm.amdgcn.raw.buffer.load.v2f32");
__device__ float llvm_amdgcn_raw_buffer_load_f32(int32x4_t srsrc, int voffset,
                                                 int soffset, int aux)
    __asm("llvm.amdgcn.raw.buffer.load.f32");

__device__ inline int32x4_t make_srd(const void* p, unsigned bytes) {
    const unsigned long long a = (unsigned long long)p;
    int32x4_t r;
    r.x = (int)(a & 0xffffffffull);
    r.y = (int)(a >> 32);
    r.z = (int)bytes;
    r.w = 0x00020000;
    return r;
}

#if __has_builtin(__builtin_amdgcn_exp2f)
#define FAST_EXP2(x) __builtin_amdgcn_exp2f(x)
#define KLOG2E 1.44269504088896340736f
#else
#define FAST_EXP2(x) __expf(x)
#define KLOG2E 1.0f
#endif

// Block: 512 threads = 8 waves over one 32(w) x 4(h) pixel tile.
// Phase 0: stage x halo tile (6 rows x 34 cols x 64 c) + Wk into LDS as fp16,
//          c-major granule-swizzled (R5's verified fragment layout; staging
//          done per-row c-gathers so L1 working set stays resident).
// Phase 1: k-conv on MFMA: wave g owns px-group (gy=g>>1, gx=g&1): 9 taps x
//          2 c-halves = 18 x mfma_f32_16x16x32_f16 -> k[16d x 16px] directly
//          (no partials, no reduce). Bias+relu+log2e -> k_lds.
// Phase 2: q-conv + v + packed softmax over pixel pairs (R9 verbatim).
// LDS: xt 26112 + wk 18432 + k 8192 = 52736 B -> 2 blocks/CU (grid 512).
__global__ __launch_bounds__(512, 4) void gatev_fused(
    const float* __restrict__ x, const float* __restrict__ y,
    const float* __restrict__ z,
    const float* __restrict__ Wq, const float* __restrict__ bq,
    const float* __restrict__ Wk, const float* __restrict__ bk,
    const float* __restrict__ wv, const float* __restrict__ bv,
    float* __restrict__ out)
{
    __shared__ __align__(16) unsigned char smem[52736];
    unsigned short* xt   = (unsigned short*)smem;            // [pos6x34][c64] fp16 swz
    unsigned short* wkl  = (unsigned short*)(smem + 26112);  // [t9][d16][c64] fp16 swz
    float*          klds = (float*)(smem + 44544);           // [d16][p128] f32

    const int tid  = threadIdx.x;
    const int g    = __builtin_amdgcn_readfirstlane(tid >> 6);
    const int lane = tid & 63;
    const int px16 = lane & 15, py = lane >> 4;
    const int b    = blockIdx.z;
    const int h0   = blockIdx.y * 4;
    const int w0b  = blockIdx.x * 32;
    const int w0   = w0b + px16 * 2;               // even, this lane's pixel pair
    const int h    = h0 + py;
    const int pix  = h * WW + w0;
    const int p0   = py * 32 + px16 * 2;           // pixel-linear in tile

    const int32x4_t rx = make_srd(x, TOTBYTES);
    const int32x4_t ry = make_srd(y, TOTBYTES);
    const int32x4_t rz = make_srd(z, TOTBYTES);

    const int base = b * CC * HWB;
    const int c0   = __builtin_amdgcn_readfirstlane(g * 8);

    // ============ phase 0a: stage x halo tile -> fp16 LDS (c-major) =========
    {
        const int c  = tid & 63;
        const int jj = tid >> 6;                   // [0,8): col-pair slot
        const int so = base + c * HWB;
        // interior cols 1..32 as dwordx2 pairs (always col-in-bounds)
#pragma unroll
        for (int r6 = 0; r6 < 6; ++r6) {
            const int ir    = h0 - 1 + r6;
            const bool rok  = (unsigned)ir < (unsigned)HH;
#pragma unroll
            for (int s = 0; s < 2; ++s) {
                const int cp  = jj + 8 * s;        // [0,16)
                const int col = 1 + 2 * cp;        // 1,3,...,31
                const int ic0 = w0b + 2 * cp;      // in [w0b, w0b+30] -> in-bounds
                const int voff = rok ? (ir * WW + ic0) * 4 : OOB_SENT;
                const floatx2 v = llvm_amdgcn_raw_buffer_load_v2f32(rx, voff, so, 0);
                const int pos0 = r6 * 34 + col;
                const unsigned short h0v = __builtin_bit_cast(unsigned short, (_Float16)v.x);
                const unsigned short h1v = __builtin_bit_cast(unsigned short, (_Float16)v.y);
                xt[pos0 * 64       + (((c >> 3) ^ (col & 7)) << 3)       + (c & 7)] = h0v;
                xt[(pos0 + 1) * 64 + (((c >> 3) ^ ((col + 1) & 7)) << 3) + (c & 7)] = h1v;
            }
        }
        // edge col 0 (ic = w0b-1) and col 33 (ic = w0b+32)
        if (tid < 384) {
            const int cc = tid & 63;
            const int r6 = tid >> 6;               // [0,6)
            const int ir = h0 - 1 + r6;
            const bool rok = (unsigned)ir < (unsigned)HH;
            const int soc = base + cc * HWB;
            {
                const int ic = w0b - 1;
                const int voff = (rok && ic >= 0) ? (ir * WW + ic) * 4 : OOB_SENT;
                const float v = llvm_amdgcn_raw_buffer_load_f32(rx, voff, soc, 0);
                xt[(r6 * 34 + 0) * 64 + ((cc >> 3) << 3) + (cc & 7)] =
                    __builtin_bit_cast(unsigned short, (_Float16)v);
            }
            {
                const int ic = w0b + 32;
                const int voff = (rok && ic < WW) ? (ir * WW + ic) * 4 : OOB_SENT;
                const float v = llvm_amdgcn_raw_buffer_load_f32(rx, voff, soc, 0);
                xt[(r6 * 34 + 33) * 64 + (((cc >> 3) ^ 1) << 3) + (cc & 7)] =
                    __builtin_bit_cast(unsigned short, (_Float16)v);
            }
        }
    }

    // ============ phase 0b: stage Wk -> fp16 LDS [t][d][c] swizzled =========
#pragma unroll
    for (int rep = 0; rep < 9; ++rep) {
        const int idx2 = tid + rep * 512;          // pair index, 4608 total
        const int e0   = idx2 * 2;
        const int c    = e0 & 63;                  // even
        const int d    = (e0 >> 6) & 15;
        const int t    = e0 >> 10;                 // [0,9)
        const float a  = Wk[(d * CC + c) * 9 + t];
        const float b2 = Wk[(d * CC + c + 1) * 9 + t];
        const unsigned short ua = __builtin_bit_cast(unsigned short, (_Float16)a);
        const unsigned short ub = __builtin_bit_cast(unsigned short, (_Float16)b2);
        const int gsw  = ((c >> 3) ^ (d & 7));
        const int addr = (t * 16 + d) * 64 + gsw * 8 + (c & 7);
        *(unsigned*)(wkl + addr) = (unsigned)ua | ((unsigned)ub << 16);
    }
    __syncthreads();

    // ============ phase 1: k-conv via MFMA (wave owns 16-px group) ==========
    {
        const int gy = g >> 1;       // row in tile
        const int gx = g & 1;        // 16-px column group
        const int m  = lane & 15;    // A: d row | B: px col
        const int q  = lane >> 4;    // K quadrant

        floatx4 acc = {0.f, 0.f, 0.f, 0.f};
#pragma unroll
        for (int cv = 0; cv < 2; ++cv) {
#pragma unroll
            for (int t = 0; t < 9; ++t) {
                const int trow = t / 3, tcol = t % 3;
                const int ga = (cv * 4 + q) ^ (m & 7);
                const f16x8 af = *(const f16x8*)(wkl + ((t * 16 + m) * 64 + ga * 8));
                const int col = gx * 16 + m + tcol;
                const int pos = (gy + trow) * 34 + col;
                const int gb  = (cv * 4 + q) ^ (col & 7);
                const f16x8 bf = *(const f16x8*)(xt + (pos * 64 + gb * 8));
                acc = __builtin_amdgcn_mfma_f32_16x16x32_f16(af, bf, acc, 0, 0, 0);
            }
        }
        // D: col(px) = m, row(d) = q*4 + i
        const int p = gy * 32 + gx * 16 + m;
#pragma unroll
        for (int i = 0; i < 4; ++i) {
            const int d = q * 4 + i;
            klds[d * 128 + p] = fmaxf(acc[i] + bk[d], 0.f) * KLOG2E;
        }
    }
    __syncthreads();

    // ============ phase 2: q, v, softmax, packed over pixel pair (R9) =======
    const int colb = (w0 > 0 ? w0 - 1 : 0) * 4;
    int rowB[3];
#pragma unroll
    for (int r = 0; r < 3; ++r) {
        const int rr = h - 1 + r;
        rowB[r] = (rr >= 0 && rr < HH) ? rr * WW * 4 + colb : OOB_SENT;
    }
    const float mL = (w0 > 0) ? 1.f : 0.f;
    const float mR = (w0 + 2 < WW) ? 1.f : 0.f;
    const bool  w0e = (w0 == 0);

    floatx2 kl2[16];
#pragma unroll
    for (int d = 0; d < KD; ++d)
        kl2[d] = *(const floatx2*)&klds[d * 128 + p0];

    auto mktaps = [&](const floatx4& f, float (&s)[4]) {
        s[0] = f.x * mL;
        s[1] = w0e ? f.x : f.y;
        s[2] = w0e ? f.y : f.z;
        s[3] = (w0e ? f.z : f.w) * mR;
    };

    auto process = [&](const floatx4 (&f)[3], floatx2 z2, int c) {
        const float* wq = Wq + c * 9;                    // uniform -> s_load
        float s[3][4];
#pragma unroll
        for (int r = 0; r < 3; ++r) mktaps(f[r], s[r]);
        floatx2 q2 = {bq[c], bq[c]};
#pragma unroll
        for (int t = 0; t < 9; ++t) {
            const int tr = t / 3, tc = t % 3;
            const floatx2 tp2 = {s[tr][tc], s[tr][tc + 1]};
            const floatx2 wq2 = {wq[t], wq[t]};
            q2 = __builtin_elementwise_fma(wq2, tp2, q2);
        }
        const floatx2 zero2 = {0.f, 0.f};
        q2 = __builtin_elementwise_max(q2, zero2);

        floatx2 num2 = zero2, den2 = zero2;
#pragma unroll
        for (int d = 0; d < KD; ++d) {
            const floatx2 s2 = q2 * kl2[d];
            floatx2 e2;
            e2.x = FAST_EXP2(s2.x);
            e2.y = FAST_EXP2(s2.y);
            const floatx2 wv2 = {wv[d], wv[d]};
            const floatx2 bv2 = {bv[d], bv[d]};
            const floatx2 v2 = __builtin_elementwise_max(
                __builtin_elementwise_fma(z2, wv2, bv2), zero2);
            num2 = __builtin_elementwise_fma(e2, v2, num2);
            den2 = den2 + e2;
        }
        floatx2 o2;
        o2.x = __fdividef(num2.x, den2.x);
        o2.y = __fdividef(num2.y, den2.y);
        *(floatx2*)&out[(size_t)b * CC * HW + (size_t)c * HW + pix] = o2;
    };

    floatx4 fy0[3], fy1[3];
    floatx2 z0, z1;
    auto load3y = [&](floatx4 (&f)[3], floatx2& zz, int so) {
#pragma unroll
        for (int r = 0; r < 3; ++r)
            f[r] = llvm_amdgcn_raw_buffer_load_v4f32(ry, rowB[r], so, 0);
        zz = llvm_amdgcn_raw_buffer_load_v2f32(rz, pix * 4, so, 0);
    };

    load3y(fy0, z0, base + c0 * HWB);
#pragma unroll
    for (int cp = 0; cp < 4; ++cp) {
        load3y(fy1, z1, base + (c0 + 2 * cp + 1) * HWB);
        process(fy0, z0, c0 + 2 * cp);
        load3y(fy0, z0, base + (c0 + 2 * cp + 2) * HWB); // tail SRD-bounded
        process(fy1, z1, c0 + 2 * cp + 1);
    }
}

extern "C" void kernel_launch(void* const* d_in, const int* in_sizes, int n_in,
                              void* d_out, int out_size, void* d_ws, size_t ws_size,
                              hipStream_t stream) {
    const float* x  = (const float*)d_in[0];
    const float* y  = (const float*)d_in[1];
    const float* z  = (const float*)d_in[2];
    const float* Wq = (const float*)d_in[3];
    const float* bq = (const float*)d_in[4];
    const float* Wk = (const float*)d_in[5];
    const float* bk = (const float*)d_in[6];
    const float* wv = (const float*)d_in[7];
    const float* bv = (const float*)d_in[8];
    float* out = (float*)d_out;

    dim3 grid(WW / 32, HH / 4, 4);   // (4, 32, 4) = 512 blocks = 2/CU
    dim3 block(512);                 // 8 waves
    hipLaunchKernelGGL(gatev_fused, grid, block, 0, stream,
                       x, y, z, Wq, bq, Wk, bk, wv, bv, out);
}

// Round 11
// 43.793 us; speedup vs baseline: 2.6471x; 2.6471x over previous
//
#include <hip/hip_runtime.h>

#define HH 128
#define WW 128
#define CC 64
#define KD 16
#define HW (HH * WW)
#define HWB (HW * 4)
#define TOTBYTES (4u * CC * HW * 4u)   // B=4 * C=64 * H*W * 4B = 16.78 MB
#define OOB_SENT 0x40000000            // always-OOB voffset -> HW returns 0

typedef __attribute__((ext_vector_type(4))) int   int32x4_t;
typedef __attribute__((ext_vector_type(4))) float floatx4;
typedef __attribute__((ext_vector_type(2))) float floatx2;

__device__ floatx4 llvm_amdgcn_raw_buffer_load_v4f32(int32x4_t srsrc, int voffset,
                                                     int soffset, int aux)
    __asm("llvm.amdgcn.raw.buffer.load.v4f32");
__device__ floatx2 llvm_amdgcn_raw_buffer_load_v2f32(int32x4_t srsrc, int voffset,
                                                     int soffset, int aux)
    __asm("llvm.amdgcn.raw.buffer.load.v2f32");

__device__ inline int32x4_t make_srd(const void* p, unsigned bytes) {
    const unsigned long long a = (unsigned long long)p;
    int32x4_t r;
    r.x = (int)(a & 0xffffffffull);
    r.y = (int)(a >> 32);
    r.z = (int)bytes;
    r.w = 0x00020000;
    return r;
}

#if __has_builtin(__builtin_amdgcn_exp2f)
#define FAST_EXP2(x) __builtin_amdgcn_exp2f(x)
#define KLOG2E 1.44269504088896340736f
#else
#define FAST_EXP2(x) __expf(x)
#define KLOG2E 1.0f
#endif

// Block: 512 threads = 8 waves over one 32(w) x 4(h) pixel tile; each lane
// owns a horizontal pixel pair. R9 structure + 3-deep channel pipelines
// (2 channels of loads in flight; VGPR headroom to 128 is free at 2 blocks/CU)
// + interior-column specialization (blockIdx.x in {1,2} skips edge masks).
// Phase 0: stage Wk -> LDS [cg][ci][t][d16] (conflict-free mapping).
// Phase 1: wave g: channels [8g,8g+8) of x, 16 d as 8 d-pair floatx2 accs
//          per pixel (v_pk_fma_f32); partials [g][d][p128] -> 8-way reduce.
// Phase 2: q-conv + v + softmax packed over the pixel pair, 3-deep pipeline.
__global__ __launch_bounds__(512, 4) void gatev_fused(
    const float* __restrict__ x, const float* __restrict__ y,
    const float* __restrict__ z,
    const float* __restrict__ Wq, const float* __restrict__ bq,
    const float* __restrict__ Wk, const float* __restrict__ bk,
    const float* __restrict__ wv, const float* __restrict__ bv,
    float* __restrict__ out)
{
    __shared__ float lds[16384];   // 64 KB: Wk(36KB) -> partials(64KB) -> k(8KB)

    const int tid  = threadIdx.x;
    const int g    = __builtin_amdgcn_readfirstlane(tid >> 6);
    const int lane = tid & 63;
    const int px16 = lane & 15, py = lane >> 4;
    const int b    = blockIdx.z;
    const int w0   = blockIdx.x * 32 + px16 * 2;   // even
    const int h    = blockIdx.y * 4 + py;
    const int pix  = h * WW + w0;
    const int p0   = py * 32 + px16 * 2;           // pixel-linear in tile

    const int32x4_t rx = make_srd(x, TOTBYTES);
    const int32x4_t ry = make_srd(y, TOTBYTES);
    const int32x4_t rz = make_srd(z, TOTBYTES);

    // One float4 per tap-row at col max(w0-1,0): covers cols w0-1..w0+2.
    const int colb = (w0 > 0 ? w0 - 1 : 0) * 4;
    int rowB[3];
#pragma unroll
    for (int r = 0; r < 3; ++r) {
        const int rr = h - 1 + r;
        rowB[r] = (rr >= 0 && rr < HH) ? rr * WW * 4 + colb : OOB_SENT;
    }
    const bool  intw = (blockIdx.x > 0) & (blockIdx.x < (WW / 32 - 1));
    const float mL = (w0 > 0) ? 1.f : 0.f;           // px0 left tap
    const float mR = (w0 + 2 < WW) ? 1.f : 0.f;      // px1 right tap
    const bool  w0e = (w0 == 0);

    const int base = b * CC * HWB;
    const int c0   = __builtin_amdgcn_readfirstlane(g * 8);

    // ---------------- phase 0: stage Wk -> LDS [cg][ci][t][d16] -------------
    {
        const int d  = tid & 15;
        const int cA = tid >> 4;           // [0,32)
#pragma unroll
        for (int half = 0; half < 2; ++half) {
            const int c   = cA + half * 32;
            const int dst = (c >> 3) * 1152 + (c & 7) * 144 + d;
            const float* src = Wk + (d * CC + c) * 9;
#pragma unroll
            for (int t = 0; t < 9; ++t)
                lds[dst + t * 16] = src[t];
        }
    }
    __syncthreads();

    // 4 tap columns per row: s0 = w0-1, s1 = w0, s2 = w0+1, s3 = w0+2
    auto mktaps = [&](const floatx4& f, float (&s)[4]) {
        if (intw) { s[0] = f.x; s[1] = f.y; s[2] = f.z; s[3] = f.w; }
        else {
            s[0] = f.x * mL;
            s[1] = w0e ? f.x : f.y;
            s[2] = w0e ? f.y : f.z;
            s[3] = (w0e ? f.z : f.w) * mR;
        }
    };

    // ---------------- phase 1: packed partial k, 8 channels, 2 px ----------
    floatx2 aP0[8], aP1[8];                // [d-pair] per pixel
#pragma unroll
    for (int i = 0; i < 8; ++i) { aP0[i] = (floatx2){0.f, 0.f}; aP1[i] = (floatx2){0.f, 0.f}; }

    auto load3 = [&](floatx4 (&f)[3], int so) {
#pragma unroll
        for (int r = 0; r < 3; ++r)
            f[r] = llvm_amdgcn_raw_buffer_load_v4f32(rx, rowB[r], so, 0);
    };
    auto compute = [&](const floatx4 (&f)[3], int wb) {
        float s[3][4];
#pragma unroll
        for (int r = 0; r < 3; ++r) mktaps(f[r], s[r]);
#pragma unroll
        for (int t = 0; t < 9; ++t) {
            const int tr = t / 3, tc = t % 3;
            const floatx2 t0 = {s[tr][tc],     s[tr][tc]};
            const floatx2 t1 = {s[tr][tc + 1], s[tr][tc + 1]};
#pragma unroll
            for (int j = 0; j < 4; ++j) {    // uniform ds_read_b128
                const floatx4 w4 = *(const floatx4*)&lds[wb + t * 16 + j * 4];
                const floatx2 lo = __builtin_shufflevector(w4, w4, 0, 1);
                const floatx2 hi = __builtin_shufflevector(w4, w4, 2, 3);
                aP0[2 * j + 0] = __builtin_elementwise_fma(lo, t0, aP0[2 * j + 0]);
                aP0[2 * j + 1] = __builtin_elementwise_fma(hi, t0, aP0[2 * j + 1]);
                aP1[2 * j + 0] = __builtin_elementwise_fma(lo, t1, aP1[2 * j + 0]);
                aP1[2 * j + 1] = __builtin_elementwise_fma(hi, t1, aP1[2 * j + 1]);
            }
        }
    };

    const int wbase = g * 1152;
    {
        floatx4 fb[3][3];                  // 3-deep rotating channel pipeline
        load3(fb[0], base + (c0 + 0) * HWB);
        load3(fb[1], base + (c0 + 1) * HWB);
#pragma unroll
        for (int ci = 0; ci < 8; ++ci) {
            load3(fb[(ci + 2) % 3], base + (c0 + ci + 2) * HWB);  // tail: SRD-bounded -> 0
            compute(fb[ci % 3], wbase + ci * 144);
        }
    }
    __syncthreads();                                     // weight reads done

    // partials [g][d][p]: (p0, p0+1) contiguous -> b64 writes
#pragma unroll
    for (int i = 0; i < 8; ++i) {
        *(floatx2*)&lds[g * 2048 + (2 * i + 0) * 128 + p0] = (floatx2){aP0[i].x, aP1[i].x};
        *(floatx2*)&lds[g * 2048 + (2 * i + 1) * 128 + p0] = (floatx2){aP0[i].y, aP1[i].y};
    }
    __syncthreads();

    // ---------------- reduce 8 partials -> k[d][p] (in place) ---------------
#pragma unroll
    for (int rep = 0; rep < 4; ++rep) {
        const int idx = tid + rep * 512;                 // = d*128 + p
        float s = lds[idx];
#pragma unroll
        for (int gg = 1; gg < 8; ++gg) s += lds[gg * 2048 + idx];
        const int d = idx >> 7;                          // wave-uniform
        lds[idx] = fmaxf(s + bk[d], 0.f) * KLOG2E;
    }
    __syncthreads();

    // ---------------- phase 2: q, v, softmax, packed over pixel pair --------
    floatx2 kl2[16];                                     // k for both pixels, hoisted
#pragma unroll
    for (int d = 0; d < KD; ++d)
        kl2[d] = *(const floatx2*)&lds[d * 128 + p0];

    auto process = [&](const floatx4 (&f)[3], floatx2 z2, int c) {
        const float* wq = Wq + c * 9;                    // uniform -> s_load
        float s[3][4];
#pragma unroll
        for (int r = 0; r < 3; ++r) mktaps(f[r], s[r]);
        floatx2 q2 = {bq[c], bq[c]};
#pragma unroll
        for (int t = 0; t < 9; ++t) {
            const int tr = t / 3, tc = t % 3;
            const floatx2 tp2 = {s[tr][tc], s[tr][tc + 1]};
            const floatx2 wq2 = {wq[t], wq[t]};
            q2 = __builtin_elementwise_fma(wq2, tp2, q2);
        }
        const floatx2 zero2 = {0.f, 0.f};
        q2 = __builtin_elementwise_max(q2, zero2);

        floatx2 num2 = zero2, den2 = zero2;
#pragma unroll
        for (int d = 0; d < KD; ++d) {
            const floatx2 s2 = q2 * kl2[d];              // v_pk_mul_f32
            floatx2 e2;
            e2.x = FAST_EXP2(s2.x);
            e2.y = FAST_EXP2(s2.y);
            const floatx2 wv2 = {wv[d], wv[d]};
            const floatx2 bv2 = {bv[d], bv[d]};
            const floatx2 v2 = __builtin_elementwise_max(
                __builtin_elementwise_fma(z2, wv2, bv2), zero2);
            num2 = __builtin_elementwise_fma(e2, v2, num2);
            den2 = den2 + e2;
        }
        floatx2 o2;
        o2.x = __fdividef(num2.x, den2.x);
        o2.y = __fdividef(num2.y, den2.y);
        *(floatx2*)&out[(size_t)b * CC * HW + (size_t)c * HW + pix] = o2;
    };

    auto load3y = [&](floatx4 (&f)[3], floatx2& zz, int so) {
#pragma unroll
        for (int r = 0; r < 3; ++r)
            f[r] = llvm_amdgcn_raw_buffer_load_v4f32(ry, rowB[r], so, 0);
        zz = llvm_amdgcn_raw_buffer_load_v2f32(rz, pix * 4, so, 0);
    };

    {
        floatx4 gy[3][3];                  // 3-deep rotating channel pipeline
        floatx2 gz[3];
        load3y(gy[0], gz[0], base + (c0 + 0) * HWB);
        load3y(gy[1], gz[1], base + (c0 + 1) * HWB);
#pragma unroll
        for (int ci = 0; ci < 8; ++ci) {
            load3y(gy[(ci + 2) % 3], gz[(ci + 2) % 3],
                   base + (c0 + ci + 2) * HWB);          // tail: SRD-bounded -> 0
            process(gy[ci % 3], gz[ci % 3], c0 + ci);
        }
    }
}

extern "C" void kernel_launch(void* const* d_in, const int* in_sizes, int n_in,
                              void* d_out, int out_size, void* d_ws, size_t ws_size,
                              hipStream_t stream) {
    const float* x  = (const float*)d_in[0];
    const float* y  = (const float*)d_in[1];
    const float* z  = (const float*)d_in[2];
    const float* Wq = (const float*)d_in[3];
    const float* bq = (const float*)d_in[4];
    const float* Wk = (const float*)d_in[5];
    const float* bk = (const float*)d_in[6];
    const float* wv = (const float*)d_in[7];
    const float* bv = (const float*)d_in[8];
    float* out = (float*)d_out;

    dim3 grid(WW / 32, HH / 4, 4);   // (4, 32, 4) = 512 blocks = 2/CU
    dim3 block(512);                 // 8 waves
    hipLaunchKernelGGL(gatev_fused, grid, block, 0, stream,
                       x, y, z, Wq, bq, Wk, bk, wv, bv, out);
}